// Round 6
// baseline (61.198 us; speedup 1.0000x reference)
//
#include <hip/hip_runtime.h>
#include <math.h>

#define H_IN   136
#define W_IN   200
#define HWP    (H_IN * W_IN)       // 27200
#define OH     272
#define OW     400
#define CH     8
#define CIN    8
#define NPARAM 169
#define NEG_LOG2E (-1.4426950408889634f)
#define NGRP   (HWP / 8)           // 3400 8-px groups per instance

// DIAGNOSTIC ROUND: A and B are byte-identical to R5. We launch A twice
// (second into dead scratch) so total = 2A + B; with R5's A + B = 42.9 us,
// A = dur_us - 42.9 exactly. This resolves which kernel owns the ~30 us
// that three consecutive A-rewrites failed to move.

// ---------------- Kernel A: per-instance MLP -> t-space logits ----------------
__global__ __launch_bounds__(256, 3) void logits_kernel(
    const float* __restrict__ mask_feats,   // (N, 8, H, W)
    const float* __restrict__ params,       // (n_inst, 169)
    const float* __restrict__ locations,    // (n_inst, 2)
    const int*   __restrict__ im_inds,      // (n_inst,)
    const int*   __restrict__ fpn_levels,   // (n_inst,)
    const float* __restrict__ soi_tab,      // (5,)
    float* __restrict__ lg)                 // (n_inst, 27200)
{
    const int inst = blockIdx.y;
    const int u    = blockIdx.x * 256 + threadIdx.x;
    if (u >= NGRP) return;
    const int p = u * 8;
    const int r = p / W_IN;
    const int c = p - r * W_IN;

    const float* P = params + inst * NPARAM;
    const float loc_x   = locations[2 * inst];
    const float loc_y   = locations[2 * inst + 1];
    const float inv_soi = 1.0f / soi_tab[fpn_levels[inst]];
    const float* F  = mask_feats + (size_t)im_inds[inst] * (CIN * HWP);
    float*       Lo = lg + (size_t)inst * HWP;

    float4 fa[CIN], fb[CIN];
    #pragma unroll
    for (int ch = 0; ch < CIN; ++ch) {
        const float* q = F + ch * HWP + p;
        fa[ch] = *(const float4*)q;
        fb[ch] = *(const float4*)(q + 4);
    }

    const float ry = (loc_y - (float)(r * 8 + 4)) * inv_soi;
    const float dx = -8.0f * inv_soi;
    float rx[8];
    rx[0] = (loc_x - (float)(c * 8 + 4)) * inv_soi;
    #pragma unroll
    for (int j = 1; j < 8; ++j) rx[j] = rx[j - 1] + dx;

    float h0[CH][8];
    #pragma unroll
    for (int o = 0; o < CH; ++o) {
        const float b  = P[152 + o];
        const float wx = P[o * 10 + 0];
        const float wy = P[o * 10 + 1];
        float a[8];
        #pragma unroll
        for (int j = 0; j < 8; ++j) a[j] = fmaf(wx, rx[j], fmaf(wy, ry, b));
        #pragma unroll
        for (int i = 0; i < CIN; ++i) {
            const float w = P[o * 10 + 2 + i];
            a[0] = fmaf(w, fa[i].x, a[0]); a[1] = fmaf(w, fa[i].y, a[1]);
            a[2] = fmaf(w, fa[i].z, a[2]); a[3] = fmaf(w, fa[i].w, a[3]);
            a[4] = fmaf(w, fb[i].x, a[4]); a[5] = fmaf(w, fb[i].y, a[5]);
            a[6] = fmaf(w, fb[i].z, a[6]); a[7] = fmaf(w, fb[i].w, a[7]);
        }
        #pragma unroll
        for (int j = 0; j < 8; ++j) h0[o][j] = fmaxf(a[j], 0.0f);
    }

    float h1[CH][8];
    #pragma unroll
    for (int o = 0; o < CH; ++o) {
        const float b = P[160 + o];
        float a[8];
        #pragma unroll
        for (int j = 0; j < 8; ++j) a[j] = b;
        #pragma unroll
        for (int i = 0; i < CH; ++i) {
            const float w = P[80 + o * CH + i];
            #pragma unroll
            for (int j = 0; j < 8; ++j) a[j] = fmaf(w, h0[i][j], a[j]);
        }
        #pragma unroll
        for (int j = 0; j < 8; ++j) h1[o][j] = fmaxf(a[j], 0.0f);
    }

    float t[8];
    const float b2 = NEG_LOG2E * P[168];
    #pragma unroll
    for (int j = 0; j < 8; ++j) t[j] = b2;
    #pragma unroll
    for (int i = 0; i < CH; ++i) {
        const float w = NEG_LOG2E * P[144 + i];
        #pragma unroll
        for (int j = 0; j < 8; ++j) t[j] = fmaf(w, h1[i][j], t[j]);
    }

    *(float4*)(Lo + p)     = make_float4(t[0], t[1], t[2], t[3]);
    *(float4*)(Lo + p + 4) = make_float4(t[4], t[5], t[6], t[7]);
}

// ---------------- Kernel B: 2x aligned-bilinear upsample + sigmoid ----------------
__global__ __launch_bounds__(256) void upsample_kernel(
    const float* __restrict__ lg,           // (n_inst, 27200) t-space
    float* __restrict__ out)                // (n_inst, 272, 400)
{
    int g = blockIdx.x * 256 + threadIdx.x;     // < 1,740,800
    int inst = g / (OH * (OW / 8));
    int q    = g - inst * (OH * (OW / 8));
    int y    = q / (OW / 8);
    int t    = q - y * (OW / 8);

    const float* L = lg + (size_t)inst * HWP;

    int   jy  = max(y - 1, 0);
    int   a0i = jy >> 1;
    float fy  = (jy & 1) ? 0.5f : 0.0f;
    int r0 = min(a0i,     H_IN - 1);
    int r1 = min(a0i + 1, H_IN - 1);

    int cm = 4 * t;                              // <= 196
    int cp = max(cm - 4, 0);
    float4 m0 = *(const float4*)(L + r0 * W_IN + cm);
    float4 m1 = *(const float4*)(L + r1 * W_IN + cm);
    float4 p0 = *(const float4*)(L + r0 * W_IN + cp);
    float4 p1 = *(const float4*)(L + r1 * W_IN + cp);

    float B = fmaf(fy, m1.x - m0.x, m0.x);
    float C = fmaf(fy, m1.y - m0.y, m0.y);
    float D = fmaf(fy, m1.z - m0.z, m0.z);
    float E = fmaf(fy, m1.w - m0.w, m0.w);
    float A = (t == 0) ? B : fmaf(fy, p1.w - p0.w, p0.w);

    float4 r0v, r1v;
    r0v.x = __builtin_amdgcn_rcpf(1.0f + __builtin_amdgcn_exp2f(0.5f * (A + B)));
    r0v.y = __builtin_amdgcn_rcpf(1.0f + __builtin_amdgcn_exp2f(B));
    r0v.z = __builtin_amdgcn_rcpf(1.0f + __builtin_amdgcn_exp2f(0.5f * (B + C)));
    r0v.w = __builtin_amdgcn_rcpf(1.0f + __builtin_amdgcn_exp2f(C));
    r1v.x = __builtin_amdgcn_rcpf(1.0f + __builtin_amdgcn_exp2f(0.5f * (C + D)));
    r1v.y = __builtin_amdgcn_rcpf(1.0f + __builtin_amdgcn_exp2f(D));
    r1v.z = __builtin_amdgcn_rcpf(1.0f + __builtin_amdgcn_exp2f(0.5f * (D + E)));
    r1v.w = __builtin_amdgcn_rcpf(1.0f + __builtin_amdgcn_exp2f(E));

    float* Op = out + (size_t)inst * (OH * OW) + y * OW + 8 * t;
    *(float4*)(Op)     = r0v;
    *(float4*)(Op + 4) = r1v;
}

extern "C" void kernel_launch(void* const* d_in, const int* in_sizes, int n_in,
                              void* d_out, int out_size, void* d_ws, size_t ws_size,
                              hipStream_t stream) {
    const float* mask_feats = (const float*)d_in[0];
    const float* params     = (const float*)d_in[1];
    const float* locations  = (const float*)d_in[2];
    const int*   im_inds    = (const int*)d_in[3];
    const int*   fpn_levels = (const int*)d_in[4];
    const float* soi_tab    = (const float*)d_in[5];

    const int n_inst = in_sizes[1] / NPARAM;   // 128
    float* lg  = (float*)d_ws;                               // 13.9 MB
    float* lg2 = (float*)((char*)d_ws + (size_t)(128 << 20)); // dead scratch (ws >= 256 MiB)

    dim3 gA((NGRP + 255) / 256, n_inst);       // (14, 128)
    // Real producer
    logits_kernel<<<gA, 256, 0, stream>>>(
        mask_feats, params, locations, im_inds, fpn_levels, soi_tab, lg);
    // Diagnostic duplicate (dead output): total = 2A + B
    logits_kernel<<<gA, 256, 0, stream>>>(
        mask_feats, params, locations, im_inds, fpn_levels, soi_tab, lg2);

    const int total_units = n_inst * OH * (OW / 8);      // 1,740,800
    upsample_kernel<<<total_units / 256, 256, 0, stream>>>(lg, (float*)d_out);
}

// Round 7
// 36.799 us; speedup vs baseline: 1.6630x; 1.6630x over previous
//
#include <hip/hip_runtime.h>
#include <math.h>

#define H_IN   136
#define W_IN   200
#define HWP    (H_IN * W_IN)       // 27200
#define OH     272
#define OW     400
#define CH     8
#define CIN    8
#define NPARAM 169
#define NEG_LOG2E (-1.4426950408889634f)
#define NGRP   (HWP / 8)           // 3400 8-px groups per instance
#define UPB    (H_IN * (W_IN / 4)) // 6800 row-pair x quad units per instance

// Param layout per instance (169 floats):
//  [0..79] w0[8][10] | [80..143] w1[8][8] | [144..151] w2[8]
//  [152..159] b0[8]  | [160..167] b1[8]   | [168] b2

// ---------------- Kernel A: per-instance MLP -> t-space logits ----------------
// R7 change: all 169 weights staged in LDS once per block (broadcast ds_read),
// eliminating per-thread s_load churn (169 floats >> ~100-SGPR budget).
// Writes lg[inst][p] = -log2(e) * logit  (so B uses exp2 directly).
__global__ __launch_bounds__(256, 3) void logits_kernel(
    const float* __restrict__ mask_feats,   // (N, 8, H, W)
    const float* __restrict__ params,       // (n_inst, 169)
    const float* __restrict__ locations,    // (n_inst, 2)
    const int*   __restrict__ im_inds,      // (n_inst,)
    const int*   __restrict__ fpn_levels,   // (n_inst,)
    const float* __restrict__ soi_tab,      // (5,)
    float* __restrict__ lg)                 // (n_inst, 27200)
{
    __shared__ float sW[NPARAM];

    const int inst = blockIdx.y;
    const float* P = params + inst * NPARAM;
    if (threadIdx.x < NPARAM) sW[threadIdx.x] = P[threadIdx.x];
    __syncthreads();

    const int u = blockIdx.x * 256 + threadIdx.x;
    if (u >= NGRP) return;
    const int p = u * 8;
    const int r = p / W_IN;
    const int c = p - r * W_IN;

    const float loc_x   = locations[2 * inst];
    const float loc_y   = locations[2 * inst + 1];
    const float inv_soi = 1.0f / soi_tab[fpn_levels[inst]];
    const float* F  = mask_feats + (size_t)im_inds[inst] * (CIN * HWP);
    float*       Lo = lg + (size_t)inst * HWP;

    float4 fa[CIN], fb[CIN];
    #pragma unroll
    for (int ch = 0; ch < CIN; ++ch) {
        const float* q = F + ch * HWP + p;
        fa[ch] = *(const float4*)q;
        fb[ch] = *(const float4*)(q + 4);
    }

    const float ry = (loc_y - (float)(r * 8 + 4)) * inv_soi;
    const float dx = -8.0f * inv_soi;
    float rx[8];
    rx[0] = (loc_x - (float)(c * 8 + 4)) * inv_soi;
    #pragma unroll
    for (int j = 1; j < 8; ++j) rx[j] = rx[j - 1] + dx;

    float h0[CH][8];
    #pragma unroll
    for (int o = 0; o < CH; ++o) {
        const float b  = sW[152 + o];
        const float wx = sW[o * 10 + 0];
        const float wy = sW[o * 10 + 1];
        float a[8];
        #pragma unroll
        for (int j = 0; j < 8; ++j) a[j] = fmaf(wx, rx[j], fmaf(wy, ry, b));
        #pragma unroll
        for (int i = 0; i < CIN; ++i) {
            const float w = sW[o * 10 + 2 + i];
            a[0] = fmaf(w, fa[i].x, a[0]); a[1] = fmaf(w, fa[i].y, a[1]);
            a[2] = fmaf(w, fa[i].z, a[2]); a[3] = fmaf(w, fa[i].w, a[3]);
            a[4] = fmaf(w, fb[i].x, a[4]); a[5] = fmaf(w, fb[i].y, a[5]);
            a[6] = fmaf(w, fb[i].z, a[6]); a[7] = fmaf(w, fb[i].w, a[7]);
        }
        #pragma unroll
        for (int j = 0; j < 8; ++j) h0[o][j] = fmaxf(a[j], 0.0f);
    }

    float h1[CH][8];
    #pragma unroll
    for (int o = 0; o < CH; ++o) {
        const float b = sW[160 + o];
        float a[8];
        #pragma unroll
        for (int j = 0; j < 8; ++j) a[j] = b;
        #pragma unroll
        for (int i = 0; i < CH; ++i) {
            const float w = sW[80 + o * CH + i];
            #pragma unroll
            for (int j = 0; j < 8; ++j) a[j] = fmaf(w, h0[i][j], a[j]);
        }
        #pragma unroll
        for (int j = 0; j < 8; ++j) h1[o][j] = fmaxf(a[j], 0.0f);
    }

    float t[8];
    const float b2 = NEG_LOG2E * sW[168];
    #pragma unroll
    for (int j = 0; j < 8; ++j) t[j] = b2;
    #pragma unroll
    for (int i = 0; i < CH; ++i) {
        const float w = NEG_LOG2E * sW[144 + i];
        #pragma unroll
        for (int j = 0; j < 8; ++j) t[j] = fmaf(w, h1[i][j], t[j]);
    }

    *(float4*)(Lo + p)     = make_float4(t[0], t[1], t[2], t[3]);
    *(float4*)(Lo + p + 4) = make_float4(t[4], t[5], t[6], t[7]);
}

// ---------------- Kernel B: 2x aligned-bilinear upsample + sigmoid ----------------
// R7 change: one thread = 16 px (8 wide x 2 output rows). Output rows
// (2rp, 2rp+1) need only low-res rows rp-1 and rp:
//   y = 2rp+1: jy=2rp,   a0=rp,   fy=0   -> H-upsample of row rp
//   y = 2rp:   jy=2rp-1, a0=rp-1, fy=0.5 -> H-upsample of avg(row rp-1, row rp)
//   rp = 0:    jy=0 -> row 0 for both (rQ=rp handles it with no special case)
__global__ __launch_bounds__(256) void upsample_kernel(
    const float* __restrict__ lg,           // (n_inst, 27200) t-space
    float* __restrict__ out)                // (n_inst, 272, 400)
{
    const int u = blockIdx.x * 256 + threadIdx.x;
    if (u >= UPB) return;
    const int inst = blockIdx.y;
    const int rp = u / (W_IN / 4);          // 0..135
    const int t  = u - rp * (W_IN / 4);     // 0..49

    const float* L = lg + (size_t)inst * HWP;
    const int rA = rp;
    const int rQ = max(rp - 1, 0);
    const int cm = 4 * t;                   // <= 196
    const int cl = max(cm - 1, 0);

    float4 mR = *(const float4*)(L + rA * W_IN + cm);
    float4 mQ = *(const float4*)(L + rQ * W_IN + cm);
    float  pR = L[rA * W_IN + cl];
    float  pQ = L[rQ * W_IN + cl];

    // col values A..E = cols cm-1, cm, cm+1, cm+2, cm+3
    float AR = (t == 0) ? mR.x : pR;
    float AQ = (t == 0) ? mQ.x : pQ;
    float Aa = 0.5f * (AR + AQ);
    float Ba = 0.5f * (mR.x + mQ.x);
    float Ca = 0.5f * (mR.y + mQ.y);
    float Da = 0.5f * (mR.z + mQ.z);
    float Ea = 0.5f * (mR.w + mQ.w);

    // y0 = 2rp (avg row), y1 = 2rp+1 (row rA)
    float4 s0, s1, s2, s3;
    s0.x = __builtin_amdgcn_rcpf(1.0f + __builtin_amdgcn_exp2f(0.5f * (Aa + Ba)));
    s0.y = __builtin_amdgcn_rcpf(1.0f + __builtin_amdgcn_exp2f(Ba));
    s0.z = __builtin_amdgcn_rcpf(1.0f + __builtin_amdgcn_exp2f(0.5f * (Ba + Ca)));
    s0.w = __builtin_amdgcn_rcpf(1.0f + __builtin_amdgcn_exp2f(Ca));
    s1.x = __builtin_amdgcn_rcpf(1.0f + __builtin_amdgcn_exp2f(0.5f * (Ca + Da)));
    s1.y = __builtin_amdgcn_rcpf(1.0f + __builtin_amdgcn_exp2f(Da));
    s1.z = __builtin_amdgcn_rcpf(1.0f + __builtin_amdgcn_exp2f(0.5f * (Da + Ea)));
    s1.w = __builtin_amdgcn_rcpf(1.0f + __builtin_amdgcn_exp2f(Ea));

    s2.x = __builtin_amdgcn_rcpf(1.0f + __builtin_amdgcn_exp2f(0.5f * (AR + mR.x)));
    s2.y = __builtin_amdgcn_rcpf(1.0f + __builtin_amdgcn_exp2f(mR.x));
    s2.z = __builtin_amdgcn_rcpf(1.0f + __builtin_amdgcn_exp2f(0.5f * (mR.x + mR.y)));
    s2.w = __builtin_amdgcn_rcpf(1.0f + __builtin_amdgcn_exp2f(mR.y));
    s3.x = __builtin_amdgcn_rcpf(1.0f + __builtin_amdgcn_exp2f(0.5f * (mR.y + mR.z)));
    s3.y = __builtin_amdgcn_rcpf(1.0f + __builtin_amdgcn_exp2f(mR.z));
    s3.z = __builtin_amdgcn_rcpf(1.0f + __builtin_amdgcn_exp2f(0.5f * (mR.z + mR.w)));
    s3.w = __builtin_amdgcn_rcpf(1.0f + __builtin_amdgcn_exp2f(mR.w));

    float* O0 = out + (size_t)inst * (OH * OW) + (2 * rp) * OW + 8 * t;
    *(float4*)(O0)          = s0;
    *(float4*)(O0 + 4)      = s1;
    *(float4*)(O0 + OW)     = s2;
    *(float4*)(O0 + OW + 4) = s3;
}

extern "C" void kernel_launch(void* const* d_in, const int* in_sizes, int n_in,
                              void* d_out, int out_size, void* d_ws, size_t ws_size,
                              hipStream_t stream) {
    const float* mask_feats = (const float*)d_in[0];
    const float* params     = (const float*)d_in[1];
    const float* locations  = (const float*)d_in[2];
    const int*   im_inds    = (const int*)d_in[3];
    const int*   fpn_levels = (const int*)d_in[4];
    const float* soi_tab    = (const float*)d_in[5];

    const int n_inst = in_sizes[1] / NPARAM;   // 128
    float* lg = (float*)d_ws;                  // 13.9 MB

    dim3 gA((NGRP + 255) / 256, n_inst);       // (14, 128)
    logits_kernel<<<gA, 256, 0, stream>>>(
        mask_feats, params, locations, im_inds, fpn_levels, soi_tab, lg);

    dim3 gB((UPB + 255) / 256, n_inst);        // (27, 128)
    upsample_kernel<<<gB, 256, 0, stream>>>(lg, (float*)d_out);
}

// Round 8
// 29.157 us; speedup vs baseline: 2.0989x; 1.2621x over previous
//
#include <hip/hip_runtime.h>
#include <math.h>

#define H_IN   136
#define W_IN   200
#define HWP    (H_IN * W_IN)       // 27200
#define OH     272
#define OW     400
#define RB     8                   // low-res rows per strip (17 strips)
#define NSTRIP 17
#define LROWS  (RB + 1)            // +1 halo row above
#define CH     8
#define CIN    8
#define NPARAM 169
#define NEG_LOG2E (-1.4426950408889634f)

// Param layout per instance (169 floats):
//  [0..79] w0[8][10] | [80..143] w1[8][8] | [144..151] w2[8]
//  [152..159] b0[8]  | [160..167] b1[8]   | [168] b2

// Fused: phase 1 (8px/thread MLP, LDS weights) -> 9 low-res t-space rows in
// LDS; phase 2 (row-pair upsample, 16px/thread) -> sigmoid -> global.
// Eliminates the 13.6 MB lg write + ~14 MB read and lets concurrent blocks
// overlap VALU-heavy phase 1 with store-heavy phase 2.
__global__ __launch_bounds__(256, 3) void mask_head_fused(
    const float* __restrict__ mask_feats,   // (N, 8, H, W)
    const float* __restrict__ params,       // (n_inst, 169)
    const float* __restrict__ locations,    // (n_inst, 2)
    const int*   __restrict__ im_inds,      // (n_inst,)
    const int*   __restrict__ fpn_levels,   // (n_inst,)
    const float* __restrict__ soi_tab,      // (5,)
    float* __restrict__ out)                // (n_inst, 272, 400)
{
    __shared__ float sW[NPARAM];
    __shared__ float T[LROWS][W_IN];        // t = -log2e * logit, rows r0-1..r0+7

    const int inst = blockIdx.y;
    const int r0   = blockIdx.x * RB;
    const int tid  = threadIdx.x;

    const float* P = params + inst * NPARAM;
    if (tid < NPARAM) sW[tid] = P[tid];
    __syncthreads();

    // ---- Phase 1: 225 units of 8 px (9 rows x 25 units/row) ----
    if (tid < LROWS * (W_IN / 8)) {
        const int k = tid / (W_IN / 8);
        const int c = (tid - k * (W_IN / 8)) * 8;
        const int r = min(max(r0 - 1 + k, 0), H_IN - 1);

        const float loc_x   = locations[2 * inst];
        const float loc_y   = locations[2 * inst + 1];
        const float inv_soi = 1.0f / soi_tab[fpn_levels[inst]];
        const float* F = mask_feats + (size_t)im_inds[inst] * (CIN * HWP);

        float4 fa[CIN], fb[CIN];
        #pragma unroll
        for (int ch = 0; ch < CIN; ++ch) {
            const float* q = F + ch * HWP + r * W_IN + c;
            fa[ch] = *(const float4*)q;
            fb[ch] = *(const float4*)(q + 4);
        }

        const float ry = (loc_y - (float)(r * 8 + 4)) * inv_soi;
        const float dx = -8.0f * inv_soi;
        float rx[8];
        rx[0] = (loc_x - (float)(c * 8 + 4)) * inv_soi;
        #pragma unroll
        for (int j = 1; j < 8; ++j) rx[j] = rx[j - 1] + dx;

        float h0[CH][8];
        #pragma unroll
        for (int o = 0; o < CH; ++o) {
            const float b  = sW[152 + o];
            const float wx = sW[o * 10 + 0];
            const float wy = sW[o * 10 + 1];
            float a[8];
            #pragma unroll
            for (int j = 0; j < 8; ++j) a[j] = fmaf(wx, rx[j], fmaf(wy, ry, b));
            #pragma unroll
            for (int i = 0; i < CIN; ++i) {
                const float w = sW[o * 10 + 2 + i];
                a[0] = fmaf(w, fa[i].x, a[0]); a[1] = fmaf(w, fa[i].y, a[1]);
                a[2] = fmaf(w, fa[i].z, a[2]); a[3] = fmaf(w, fa[i].w, a[3]);
                a[4] = fmaf(w, fb[i].x, a[4]); a[5] = fmaf(w, fb[i].y, a[5]);
                a[6] = fmaf(w, fb[i].z, a[6]); a[7] = fmaf(w, fb[i].w, a[7]);
            }
            #pragma unroll
            for (int j = 0; j < 8; ++j) h0[o][j] = fmaxf(a[j], 0.0f);
        }

        float h1[CH][8];
        #pragma unroll
        for (int o = 0; o < CH; ++o) {
            const float b = sW[160 + o];
            float a[8];
            #pragma unroll
            for (int j = 0; j < 8; ++j) a[j] = b;
            #pragma unroll
            for (int i = 0; i < CH; ++i) {
                const float w = sW[80 + o * CH + i];
                #pragma unroll
                for (int j = 0; j < 8; ++j) a[j] = fmaf(w, h0[i][j], a[j]);
            }
            #pragma unroll
            for (int j = 0; j < 8; ++j) h1[o][j] = fmaxf(a[j], 0.0f);
        }

        float t[8];
        const float b2 = NEG_LOG2E * sW[168];
        #pragma unroll
        for (int j = 0; j < 8; ++j) t[j] = b2;
        #pragma unroll
        for (int i = 0; i < CH; ++i) {
            const float w = NEG_LOG2E * sW[144 + i];
            #pragma unroll
            for (int j = 0; j < 8; ++j) t[j] = fmaf(w, h1[i][j], t[j]);
        }

        #pragma unroll
        for (int j = 0; j < 8; ++j) T[k][c + j] = t[j];
    }
    __syncthreads();

    // ---- Phase 2: 400 units of 16 px (8 wide x 2 output rows), <=2 per thread ----
    // Output rows (2rp, 2rp+1) need low-res rows rp-1 (slot rpl) and rp (slot rpl+1).
    // Strip 0 boundary handled by phase 1's row clamp (slot 0 = row 0).
    float* O = out + (size_t)inst * (OH * OW);
    #pragma unroll
    for (int it = 0; it < 2; ++it) {
        const int s = tid + 256 * it;
        if (s < RB * (W_IN / 4)) {
            const int rpl = s / (W_IN / 4);         // 0..7
            const int t   = s - rpl * (W_IN / 4);   // 0..49
            const int cm  = 4 * t;
            const int cl  = max(cm - 1, 0);

            const float4 mR = *(const float4*)&T[rpl + 1][cm];
            const float4 mQ = *(const float4*)&T[rpl][cm];
            const float  AR = T[rpl + 1][cl];       // == mR.x when t==0
            const float  AQ = T[rpl][cl];

            const float Aa = 0.5f * (AR + AQ);
            const float Ba = 0.5f * (mR.x + mQ.x);
            const float Ca = 0.5f * (mR.y + mQ.y);
            const float Da = 0.5f * (mR.z + mQ.z);
            const float Ea = 0.5f * (mR.w + mQ.w);

            float4 s0, s1, s2, s3;
            s0.x = __builtin_amdgcn_rcpf(1.0f + __builtin_amdgcn_exp2f(0.5f * (Aa + Ba)));
            s0.y = __builtin_amdgcn_rcpf(1.0f + __builtin_amdgcn_exp2f(Ba));
            s0.z = __builtin_amdgcn_rcpf(1.0f + __builtin_amdgcn_exp2f(0.5f * (Ba + Ca)));
            s0.w = __builtin_amdgcn_rcpf(1.0f + __builtin_amdgcn_exp2f(Ca));
            s1.x = __builtin_amdgcn_rcpf(1.0f + __builtin_amdgcn_exp2f(0.5f * (Ca + Da)));
            s1.y = __builtin_amdgcn_rcpf(1.0f + __builtin_amdgcn_exp2f(Da));
            s1.z = __builtin_amdgcn_rcpf(1.0f + __builtin_amdgcn_exp2f(0.5f * (Da + Ea)));
            s1.w = __builtin_amdgcn_rcpf(1.0f + __builtin_amdgcn_exp2f(Ea));

            s2.x = __builtin_amdgcn_rcpf(1.0f + __builtin_amdgcn_exp2f(0.5f * (AR + mR.x)));
            s2.y = __builtin_amdgcn_rcpf(1.0f + __builtin_amdgcn_exp2f(mR.x));
            s2.z = __builtin_amdgcn_rcpf(1.0f + __builtin_amdgcn_exp2f(0.5f * (mR.x + mR.y)));
            s2.w = __builtin_amdgcn_rcpf(1.0f + __builtin_amdgcn_exp2f(mR.y));
            s3.x = __builtin_amdgcn_rcpf(1.0f + __builtin_amdgcn_exp2f(0.5f * (mR.y + mR.z)));
            s3.y = __builtin_amdgcn_rcpf(1.0f + __builtin_amdgcn_exp2f(mR.z));
            s3.z = __builtin_amdgcn_rcpf(1.0f + __builtin_amdgcn_exp2f(0.5f * (mR.z + mR.w)));
            s3.w = __builtin_amdgcn_rcpf(1.0f + __builtin_amdgcn_exp2f(mR.w));

            float* O0 = O + (size_t)(2 * (r0 + rpl)) * OW + 8 * t;
            *(float4*)(O0)          = s0;
            *(float4*)(O0 + 4)      = s1;
            *(float4*)(O0 + OW)     = s2;
            *(float4*)(O0 + OW + 4) = s3;
        }
    }
}

extern "C" void kernel_launch(void* const* d_in, const int* in_sizes, int n_in,
                              void* d_out, int out_size, void* d_ws, size_t ws_size,
                              hipStream_t stream) {
    const float* mask_feats = (const float*)d_in[0];
    const float* params     = (const float*)d_in[1];
    const float* locations  = (const float*)d_in[2];
    const int*   im_inds    = (const int*)d_in[3];
    const int*   fpn_levels = (const int*)d_in[4];
    const float* soi_tab    = (const float*)d_in[5];

    const int n_inst = in_sizes[1] / NPARAM;   // 128
    dim3 grid(NSTRIP, n_inst);                 // (17, 128)
    mask_head_fused<<<grid, 256, 0, stream>>>(
        mask_feats, params, locations, im_inds, fpn_levels, soi_tab, (float*)d_out);
}